// Round 1
// baseline (113.173 us; speedup 1.0000x reference)
//
#include <hip/hip_runtime.h>

// Problem constants
#define D_B 8
#define N_T 2048
#define NN  64
#define N_H 8
#define N_C 32   // u-chunks of 64

typedef __bf16 bf16;
typedef bf16 bf16x8 __attribute__((ext_vector_type(8)));
typedef bf16 bf16x4 __attribute__((ext_vector_type(4)));
typedef float f32x4 __attribute__((ext_vector_type(4)));

static __device__ __forceinline__ f32x4 mfma16(bf16x8 a, bf16x8 b, f32x4 c) {
    // D[m][n] = sum_k A[m][k]*B[k][n]
    // a_frag[j] = A[lane&15][(lane>>4)*8+j]; b_frag[j] = B[(lane>>4)*8+j][lane&15]
    // d[r] = D[(lane>>4)*4+r][lane&15]
    return __builtin_amdgcn_mfma_f32_16x16x32_bf16(a, b, c, 0, 0, 0);
}

// ---------------------------------------------------------------------------
// K1: per (b, chunk c): stage r'/Q/E to bf16 LDS; compute
//   Qr[u,i]  = sum_j r'[u,j] Q[h,i,j]   (global, row-major [b,h,u,i])
//   ErT[i,u] = sum_j r'[u,j] E[h,i,j]   (global, [b,h,i,u])
//   Rbf[t,i] = bf16(r')                 (global)
//   dG[b,c,i',i] = sum_h sum_{u in c} Qr[u,i'] Er[u,i]   (fp32, via MFMA)
// 512 threads = 8 waves: (w2 = wave&3 -> 16-row slab, g = wave>>2 -> Qr/Er role)
// ---------------------------------------------------------------------------
__global__ __launch_bounds__(512, 2) void k_pre(
    const float* __restrict__ rp, const float* __restrict__ Qm,
    const float* __restrict__ Em,
    bf16* __restrict__ Qr, bf16* __restrict__ ErT, bf16* __restrict__ Rbf,
    float* __restrict__ dG)
{
    const int c = blockIdx.x, b = blockIdx.y;
    const int tid = threadIdx.x;
    const int w = tid >> 6, l = tid & 63, q = l >> 4, l16 = l & 15;
    const int g = w >> 2, w2 = w & 3;

    __shared__ bf16 Rl[64 * 72];   // r' chunk rows [u_loc][j], stride 72
    __shared__ bf16 Ql[64 * 72];   // Q_h [i][j]
    __shared__ bf16 El[64 * 72];   // E_h [i][j]
    __shared__ bf16 QT[64 * 72];   // Qr tile transposed [i][u_loc]
    __shared__ bf16 ET[64 * 72];   // Er tile transposed [i][u_loc]

    // stage R chunk (8 elems/thread) + write Rbf
    {
        const int row = tid >> 3, col = (tid & 7) * 8;
        const float* src = rp + ((size_t)(b * N_T) + c * 64 + row) * NN + col;
        bf16x8 v;
#pragma unroll
        for (int k = 0; k < 8; k++) v[k] = (bf16)src[k];
        *(bf16x8*)&Rl[row * 72 + col] = v;
        *(bf16x8*)&Rbf[((size_t)b * N_T + c * 64 + row) * NN + col] = v;
    }

    f32x4 dg0 = {0.f, 0.f, 0.f, 0.f};
    f32x4 dg1 = {0.f, 0.f, 0.f, 0.f};

    for (int h = 0; h < N_H; h++) {
        __syncthreads();  // protect Ql/El/QT/ET overwrite vs previous iter reads
        {
            const int row = tid >> 3, col = (tid & 7) * 8;
            const float* qs = Qm + (size_t)(h * NN + row) * NN + col;
            const float* es = Em + (size_t)(h * NN + row) * NN + col;
            bf16x8 vq, ve;
#pragma unroll
            for (int k = 0; k < 8; k++) { vq[k] = (bf16)qs[k]; ve[k] = (bf16)es[k]; }
            *(bf16x8*)&Ql[row * 72 + col] = vq;
            *(bf16x8*)&El[row * 72 + col] = ve;
        }
        __syncthreads();
        // slab compute: rows u_loc = w2*16 .. +16. g==0 -> Qr, g==1 -> Er
        {
            const bf16x8 a0 = *(const bf16x8*)&Rl[(w2 * 16 + l16) * 72 + q * 8];
            const bf16x8 a1 = *(const bf16x8*)&Rl[(w2 * 16 + l16) * 72 + 32 + q * 8];
            const bf16* Bsrc = (g == 0) ? Ql : El;
#pragma unroll
            for (int ns = 0; ns < 4; ns++) {
                const bf16x8 b0 = *(const bf16x8*)&Bsrc[(ns * 16 + l16) * 72 + q * 8];
                const bf16x8 b1 = *(const bf16x8*)&Bsrc[(ns * 16 + l16) * 72 + 32 + q * 8];
                f32x4 z = {0.f, 0.f, 0.f, 0.f};
                f32x4 s = mfma16(a0, b0, z);
                s = mfma16(a1, b1, s);
                // C/D: (row u_loc = w2*16+q*4+r, col i = ns*16+l16)
                bf16x4 p;
#pragma unroll
                for (int r = 0; r < 4; r++) p[r] = (bf16)s[r];
                if (g == 0) {
#pragma unroll
                    for (int r = 0; r < 4; r++) {
                        const int u = c * 64 + w2 * 16 + q * 4 + r;
                        Qr[((size_t)(b * N_H + h) * N_T + u) * NN + ns * 16 + l16] = p[r];
                    }
                    *(bf16x4*)&QT[(ns * 16 + l16) * 72 + w2 * 16 + q * 4] = p;
                } else {
                    *(bf16x4*)&ET[(ns * 16 + l16) * 72 + w2 * 16 + q * 4] = p;
                }
            }
        }
        __syncthreads();  // QT/ET complete
        // dG accumulate: wave (w2,g) -> rows i' = w2*16.., cols g*32 + ns*16
        {
            const bf16x8 a0 = *(const bf16x8*)&QT[(w2 * 16 + l16) * 72 + q * 8];
            const bf16x8 a1 = *(const bf16x8*)&QT[(w2 * 16 + l16) * 72 + 32 + q * 8];
            {
                const int col = g * 32;
                const bf16x8 b0 = *(const bf16x8*)&ET[(col + l16) * 72 + q * 8];
                const bf16x8 b1 = *(const bf16x8*)&ET[(col + l16) * 72 + 32 + q * 8];
                dg0 = mfma16(a0, b0, dg0);
                dg0 = mfma16(a1, b1, dg0);
            }
            {
                const int col = g * 32 + 16;
                const bf16x8 b0 = *(const bf16x8*)&ET[(col + l16) * 72 + q * 8];
                const bf16x8 b1 = *(const bf16x8*)&ET[(col + l16) * 72 + 32 + q * 8];
                dg1 = mfma16(a0, b0, dg1);
                dg1 = mfma16(a1, b1, dg1);
            }
        }
        // flush ErT tile (complete after barrier above), coalesced
        {
            const int row = tid >> 3, col = (tid & 7) * 8;  // row=i, col=u_loc0
            const bf16x8 v = *(const bf16x8*)&ET[row * 72 + col];
            *(bf16x8*)&ErT[((size_t)(b * N_H + h) * NN + row) * N_T + c * 64 + col] = v;
        }
    }
    // write dG (fp32, [b,c,i',i])
    {
        float* dst = dG + (size_t)(b * N_C + c) * 4096;
#pragma unroll
        for (int r = 0; r < 4; r++) {
            dst[(w2 * 16 + q * 4 + r) * 64 + g * 32 + l16] = dg0[r];
            dst[(w2 * 16 + q * 4 + r) * 64 + g * 32 + 16 + l16] = dg1[r];
        }
    }
}

// ---------------------------------------------------------------------------
// K2: exclusive prefix scan over chunks; writes GcumT bf16 [b,c,i,i'] where
// GcumT[b,c,i,i'] = sum_{c'<c} dG[b,c',i',i]  (transposed via padded LDS)
// ---------------------------------------------------------------------------
__global__ __launch_bounds__(256) void k_scan(const float* __restrict__ dG,
                                              bf16* __restrict__ GT)
{
    const int b = blockIdx.x, tid = threadIdx.x;
    __shared__ float T[64 * 65];
    float run[16];
#pragma unroll
    for (int k = 0; k < 16; k++) run[k] = 0.f;
    for (int c = 0; c < N_C; c++) {
        const float* src = dG + (size_t)(b * N_C + c) * 4096;
        float v[16];
#pragma unroll
        for (int k = 0; k < 16; k++) v[k] = src[k * 256 + tid];  // prefetchable
#pragma unroll
        for (int k = 0; k < 16; k++) {
            const int idx = k * 256 + tid;            // idx = i'*64 + i
            T[(idx >> 6) * 65 + (idx & 63)] = run[k];
        }
        __syncthreads();
        bf16* dst = GT + (size_t)(b * N_C + c) * 4096;
#pragma unroll
        for (int k = 0; k < 16; k++) {
            const int odx = k * 256 + tid;            // odx = i*64 + i'
            dst[odx] = (bf16)T[(odx & 63) * 65 + (odx >> 6)];
        }
        __syncthreads();
#pragma unroll
        for (int k = 0; k < 16; k++) run[k] += v[k];
    }
}

// ---------------------------------------------------------------------------
// K3: per (b, t-chunk c): O = R_t * GcumT^T (prefix) + sum_h tril(R_t Qr_h^T) Er_h
// (diagonal chunk only). 8 waves: s = wave&3 t-slab, g = wave>>2 h-group {0..3},{4..7}.
// ---------------------------------------------------------------------------
__global__ __launch_bounds__(512, 2) void k_main(
    const bf16* __restrict__ Qr, const bf16* __restrict__ ErT,
    const bf16* __restrict__ Rbf, const bf16* __restrict__ GT,
    float* __restrict__ out)
{
    const int c = blockIdx.x, b = blockIdx.y;
    const int tid = threadIdx.x;
    const int w = tid >> 6, l = tid & 63, q = l >> 4, l16 = l & 15;
    const int g = w >> 2, s = w & 3;
    const int t0 = c * 64;

    __shared__ bf16 Sl[8 * 16 * 72];    // per-wave private S slab (16 x 64, stride 72)
    __shared__ float Ob[4 * 16 * 65];   // h-group-0 partial O for reduction

    bf16* Sw = &Sl[w * 16 * 72];

    // A-frags: R_t rows (t = t0 + s*16 + l16), k = i'
    const bf16x8 a0 = *(const bf16x8*)&Rbf[((size_t)b * N_T + t0 + s * 16 + l16) * NN + q * 8];
    const bf16x8 a1 = *(const bf16x8*)&Rbf[((size_t)b * N_T + t0 + s * 16 + l16) * NN + 32 + q * 8];

    f32x4 acc[4];
#pragma unroll
    for (int ns = 0; ns < 4; ns++) { f32x4 z = {0.f, 0.f, 0.f, 0.f}; acc[ns] = z; }

    for (int hh = 0; hh < 4; hh++) {
        const int h = g * 4 + hh;
        const bf16* Qrt = Qr + ((size_t)(b * N_H + h) * N_T + t0) * NN;
        const bf16* Ert = ErT + (size_t)(b * N_H + h) * NN * N_T + t0;
        // S slab: S[t_loc][u_loc] = sum_i' R[t,i'] Qr[u,i'], masked, -> LDS bf16
#pragma unroll
        for (int ns = 0; ns < 4; ns++) {
            const bf16x8 b0 = *(const bf16x8*)&Qrt[(ns * 16 + l16) * NN + q * 8];
            const bf16x8 b1 = *(const bf16x8*)&Qrt[(ns * 16 + l16) * NN + 32 + q * 8];
            f32x4 z = {0.f, 0.f, 0.f, 0.f};
            f32x4 sv = mfma16(a0, b0, z);
            sv = mfma16(a1, b1, sv);
            const int u_loc = ns * 16 + l16;
#pragma unroll
            for (int r = 0; r < 4; r++) {
                const int t_loc = s * 16 + q * 4 + r;
                const float vv = (u_loc <= t_loc) ? sv[r] : 0.f;
                Sw[(q * 4 + r) * 72 + u_loc] = (bf16)vv;
            }
        }
        // same-wave LDS RAW: DS ops are in-order per wave; read S back as A-operand
        const bf16x8 sa0 = *(const bf16x8*)&Sw[l16 * 72 + q * 8];
        const bf16x8 sa1 = *(const bf16x8*)&Sw[l16 * 72 + 32 + q * 8];
        // O += S * Er  (B from ErT [i][u] storage)
#pragma unroll
        for (int ns = 0; ns < 4; ns++) {
            const bf16x8 e0 = *(const bf16x8*)&Ert[(size_t)(ns * 16 + l16) * N_T + q * 8];
            const bf16x8 e1 = *(const bf16x8*)&Ert[(size_t)(ns * 16 + l16) * N_T + 32 + q * 8];
            acc[ns] = mfma16(sa0, e0, acc[ns]);
            acc[ns] = mfma16(sa1, e1, acc[ns]);
        }
    }
    // prefix contribution (h-group 1 only): O += R_t * Gcum  (B from GcumT [i][i'])
    if (g == 1) {
        const bf16* Gt = GT + (size_t)(b * N_C + c) * 4096;
#pragma unroll
        for (int ns = 0; ns < 4; ns++) {
            const bf16x8 g0 = *(const bf16x8*)&Gt[(ns * 16 + l16) * 64 + q * 8];
            const bf16x8 g1 = *(const bf16x8*)&Gt[(ns * 16 + l16) * 64 + 32 + q * 8];
            acc[ns] = mfma16(a0, g0, acc[ns]);
            acc[ns] = mfma16(a1, g1, acc[ns]);
        }
    }
    // reduce the two h-groups
    if (g == 0) {
#pragma unroll
        for (int ns = 0; ns < 4; ns++)
#pragma unroll
            for (int r = 0; r < 4; r++)
                Ob[(s * 16 + q * 4 + r) * 65 + ns * 16 + l16] = acc[ns][r];
    }
    __syncthreads();
    if (g == 1) {
#pragma unroll
        for (int ns = 0; ns < 4; ns++)
#pragma unroll
            for (int r = 0; r < 4; r++) {
                const float sum = acc[ns][r] + Ob[(s * 16 + q * 4 + r) * 65 + ns * 16 + l16];
                out[((size_t)b * N_T + t0 + s * 16 + q * 4 + r) * NN + ns * 16 + l16] = sum;
            }
    }
}

// ---------------------------------------------------------------------------
extern "C" void kernel_launch(void* const* d_in, const int* in_sizes, int n_in,
                              void* d_out, int out_size, void* d_ws, size_t ws_size,
                              hipStream_t stream) {
    const float* rp = (const float*)d_in[0];   // (8, 2048, 64)
    const float* Qm = (const float*)d_in[1];   // (8, 64, 64)
    const float* Em = (const float*)d_in[2];   // (8, 64, 64)
    float* out = (float*)d_out;                // (8, 2048, 64) fp32

    // ws layout (40 MiB total):
    //   Qr  bf16 [8,8,2048,64]  16 MiB
    //   ErT bf16 [8,8,64,2048]  16 MiB
    //   Rbf bf16 [8,2048,64]     2 MiB
    //   dG  f32  [8,32,64,64]    4 MiB
    //   GT  bf16 [8,32,64,64]    2 MiB
    bf16* Qr = (bf16*)d_ws;
    bf16* ErT = Qr + (size_t)D_B * N_H * N_T * NN;
    bf16* Rbf = ErT + (size_t)D_B * N_H * N_T * NN;
    float* dG = (float*)(Rbf + (size_t)D_B * N_T * NN);
    bf16* GT = (bf16*)(dG + (size_t)D_B * N_C * 4096);

    k_pre<<<dim3(N_C, D_B), 512, 0, stream>>>(rp, Qm, Em, Qr, ErT, Rbf, dG);
    k_scan<<<D_B, 256, 0, stream>>>(dG, GT);
    k_main<<<dim3(N_C, D_B), 512, 0, stream>>>(Qr, ErT, Rbf, GT, out);
}